// Round 5
// baseline (1485.014 us; speedup 1.0000x reference)
//
#include <hip/hip_runtime.h>

#define T_STEPS 500
#define N_NEUR  256
#define N_IN    256
#define N_BATCH 128

// ---------------------------------------------------------------------------
// Kernel 1 (v2): XW = X @ W_in  (M=64000,K=256,N=256), fp32 vector GEMM.
// 128x128 tile, 256 threads, 8x8 acc/thread, BK=16. Ascending-k single
// accumulator per element (same numeric class as the R3-passing GEMM).
// ---------------------------------------------------------------------------
__global__ __launch_bounds__(256) void xw_gemm2_kernel(
    const float* __restrict__ A,   // [M,256]
    const float* __restrict__ W,   // [256,256]
    float* __restrict__ C)         // [M,256]
{
    __shared__ float As[16][132];  // transposed A tile
    __shared__ float Bs[16][132];
    const int tid  = threadIdx.x;
    const int bm   = blockIdx.x;       // 0..499
    const int bn   = blockIdx.y;       // 0..1
    const int ty   = tid >> 4;         // 0..15
    const int tx   = tid & 15;         // 0..15
    const int arow = tid >> 1;         // 0..127
    const int akof = (tid & 1) * 8;    // 0 or 8
    const int brow = tid >> 4;         // 0..15
    const int bcol = (tid & 15) * 8;   // 0..120
    const float* Ab = A + (size_t)bm * 128 * 256;
    const float* Wb = W + bn * 128;

    float acc[8][8];
#pragma unroll
    for (int i = 0; i < 8; ++i)
#pragma unroll
        for (int j = 0; j < 8; ++j) acc[i][j] = 0.f;

    for (int k0 = 0; k0 < 256; k0 += 16) {
        float4 a0 = *(const float4*)(Ab + (size_t)arow * 256 + k0 + akof);
        float4 a1 = *(const float4*)(Ab + (size_t)arow * 256 + k0 + akof + 4);
        float4 b0 = *(const float4*)(Wb + (size_t)(k0 + brow) * 256 + bcol);
        float4 b1 = *(const float4*)(Wb + (size_t)(k0 + brow) * 256 + bcol + 4);
        __syncthreads();
        As[akof + 0][arow] = a0.x; As[akof + 1][arow] = a0.y;
        As[akof + 2][arow] = a0.z; As[akof + 3][arow] = a0.w;
        As[akof + 4][arow] = a1.x; As[akof + 5][arow] = a1.y;
        As[akof + 6][arow] = a1.z; As[akof + 7][arow] = a1.w;
        *(float4*)&Bs[brow][bcol]     = b0;
        *(float4*)&Bs[brow][bcol + 4] = b1;
        __syncthreads();
#pragma unroll
        for (int kk = 0; kk < 16; ++kk) {
            float av[8], bv[8];
            *(float4*)&av[0] = *(const float4*)&As[kk][ty * 8];
            *(float4*)&av[4] = *(const float4*)&As[kk][ty * 8 + 4];
            *(float4*)&bv[0] = *(const float4*)&Bs[kk][tx * 8];
            *(float4*)&bv[4] = *(const float4*)&Bs[kk][tx * 8 + 4];
#pragma unroll
            for (int i = 0; i < 8; ++i)
#pragma unroll
                for (int j = 0; j < 8; ++j)
                    acc[i][j] += av[i] * bv[j];
        }
    }
    const int crow = bm * 128 + ty * 8;
    const int ccol = bn * 128 + tx * 8;
#pragma unroll
    for (int i = 0; i < 8; ++i) {
        *(float4*)(C + (size_t)(crow + i) * 256 + ccol)     =
            make_float4(acc[i][0], acc[i][1], acc[i][2], acc[i][3]);
        *(float4*)(C + (size_t)(crow + i) * 256 + ccol + 4) =
            make_float4(acc[i][4], acc[i][5], acc[i][6], acc[i][7]);
    }
}

// ---------------------------------------------------------------------------
// Kernel 1b: wz = w_rec with zeroed diagonal + zero sentinel row 256.
// ---------------------------------------------------------------------------
__global__ void prep_wrec_kernel(const float* __restrict__ w_rec,
                                 float* __restrict__ wz)
{
    int i = blockIdx.x * 256 + threadIdx.x;   // 0 .. 257*256-1
    if (i < 256 * 256) {
        int r = i >> 8, c = i & 255;
        wz[i] = (r == c) ? 0.f : w_rec[i];
    } else {
        wz[i] = 0.f;                           // sentinel row 256
    }
}

// ---------------------------------------------------------------------------
// Kernel 2 (v4 = R3's scan2 + 16-deep upfront gather): 256 threads/batch
// (4 waves -> intra-CU TLP hides L2 latency; R4 showed 1 wave/batch is 1.5x
// WORSE). Ballot masks double-buffered in LDS, one barrier/step. Gather now
// extracts 16 indices/segment upfront -> 64 loads in flight, removing the
// serialized second chunk that ~half the steps paid. Accumulation order of
// each per-segment partial is unchanged -> bit-identical to R3.
// ---------------------------------------------------------------------------
__device__ __forceinline__ unsigned long long rfl64(unsigned long long q) {
    unsigned hi = (unsigned)__builtin_amdgcn_readfirstlane((int)(q >> 32));
    unsigned lo = (unsigned)__builtin_amdgcn_readfirstlane((int)(unsigned)q);
    return ((unsigned long long)hi << 32) | (unsigned long long)lo;
}

__global__ __launch_bounds__(256) void lsnn_scan4_kernel(
    const float* __restrict__ xw,    // [B,T,N]
    const float* __restrict__ wz,    // [257,256] diag-zeroed + zero row
    const float* __restrict__ z0, const float* __restrict__ v0,
    const float* __restrict__ a0, const float* __restrict__ lsd0,
    float* __restrict__ out)         // [4,T,B,N]
{
    const int b    = blockIdx.x;
    const int n    = threadIdx.x;
    const int lane = n & 63;
    const int wid  = n >> 6;

    __shared__ unsigned long long msk[2][4];

    const float dv   = (float)0.9512294245007140018;  // exp(-1/20) fp32
    const float omdv = 1.0f - dv;

    const int bn = b * N_NEUR + n;
    float z   = z0[bn];
    float v   = v0[bn];
    float a   = a0[bn];
    float lsd = lsd0[bn];

    {
        unsigned long long wm = __ballot(z != 0.f);
        if (lane == 0) msk[0][wid] = wm;
    }
    __syncthreads();

    float x_next = xw[((size_t)b * T_STEPS) * N_NEUR + n];
    const size_t PL = (size_t)T_STEPS * N_BATCH * N_NEUR;

    for (int t = 0; t < T_STEPS; ++t) {
        float x_cur = x_next;
        {
            int tn = (t + 1 < T_STEPS) ? t + 1 : t;
            x_next = xw[((size_t)b * T_STEPS + tn) * N_NEUR + n];
        }

        const int rb = t & 1;
        unsigned long long m0 = rfl64(msk[rb][0]);
        unsigned long long m1 = rfl64(msk[rb][1]);
        unsigned long long m2 = rfl64(msk[rb][2]);
        unsigned long long m3 = rfl64(msk[rb][3]);

        const int c0 = __popcll(m0), c1 = __popcll(m1);
        const int c2 = __popcll(m2), c3 = __popcll(m3);
        const int mx = max(max(c0, c1), max(c2, c3));

        float p0 = 0.f, p1 = 0.f, p2 = 0.f, p3 = 0.f;
        if (mx > 0) {
            // ---- fused first 16 rows per segment: 64 loads in flight -----
            int id0[16], id1[16], id2[16], id3[16];
#pragma unroll
            for (int j = 0; j < 16; ++j) {
                id0[j] = m0 ? (__builtin_ctzll(m0) + 0)   : 256;  m0 &= m0 - 1;
                id1[j] = m1 ? (__builtin_ctzll(m1) + 64)  : 256;  m1 &= m1 - 1;
                id2[j] = m2 ? (__builtin_ctzll(m2) + 128) : 256;  m2 &= m2 - 1;
                id3[j] = m3 ? (__builtin_ctzll(m3) + 192) : 256;  m3 &= m3 - 1;
            }
            float w0[16], w1[16], w2[16], w3[16];
#pragma unroll
            for (int j = 0; j < 16; ++j) {
                w0[j] = wz[id0[j] * N_NEUR + n];
                w1[j] = wz[id1[j] * N_NEUR + n];
                w2[j] = wz[id2[j] * N_NEUR + n];
                w3[j] = wz[id3[j] * N_NEUR + n];
            }
#pragma unroll
            for (int j = 0; j < 16; ++j) p0 += w0[j];
#pragma unroll
            for (int j = 0; j < 16; ++j) p1 += w1[j];
#pragma unroll
            for (int j = 0; j < 16; ++j) p2 += w2[j];
#pragma unroll
            for (int j = 0; j < 16; ++j) p3 += w3[j];

            // ---- rare tail (any segment with >16 spikes) -----------------
            if (mx > 16) {
                for (int i0 = 16; i0 < mx; i0 += 8) {
                    int jd0[8], jd1[8], jd2[8], jd3[8];
#pragma unroll
                    for (int j = 0; j < 8; ++j) {
                        jd0[j] = m0 ? (__builtin_ctzll(m0) + 0)   : 256;  m0 &= m0 - 1;
                        jd1[j] = m1 ? (__builtin_ctzll(m1) + 64)  : 256;  m1 &= m1 - 1;
                        jd2[j] = m2 ? (__builtin_ctzll(m2) + 128) : 256;  m2 &= m2 - 1;
                        jd3[j] = m3 ? (__builtin_ctzll(m3) + 192) : 256;  m3 &= m3 - 1;
                    }
                    float u0[8], u1[8], u2[8], u3[8];
#pragma unroll
                    for (int j = 0; j < 8; ++j) {
                        u0[j] = wz[jd0[j] * N_NEUR + n];
                        u1[j] = wz[jd1[j] * N_NEUR + n];
                        u2[j] = wz[jd2[j] * N_NEUR + n];
                        u3[j] = wz[jd3[j] * N_NEUR + n];
                    }
#pragma unroll
                    for (int j = 0; j < 8; ++j) p0 += u0[j];
#pragma unroll
                    for (int j = 0; j < 8; ++j) p1 += u1[j];
#pragma unroll
                    for (int j = 0; j < 8; ++j) p2 += u2[j];
#pragma unroll
                    for (int j = 0; j < 8; ++j) p3 += u3[j];
                }
            }
        }
        float i_rec = ((p0 + p1) + p2) + p3;

        // ---- neuron dynamics (matches reference step exactly) -------------
        float i_in  = x_cur + i_rec;              // INTERNAL_CURRENT == 0
        float new_a = dv * a + omdv * z;
        float thr   = 0.03f + new_a * 1.8f;
        float new_v = dv * v + omdv * i_in - thr * z;
        float v_sc  = (new_v - thr) / thr;
        float zs    = (v_sc > 0.f) ? 1.f : 0.f;
        zs          = (lsd >= 2.0f) ? zs : 0.f;
        float new_lsd = (lsd + 1.f) * (1.f - zs);

        size_t o = (size_t)t * (N_BATCH * N_NEUR) + (size_t)b * N_NEUR + n;
        __builtin_nontemporal_store(zs,    out + o);
        __builtin_nontemporal_store(new_v, out + o + PL);
        __builtin_nontemporal_store(thr,   out + o + 2 * PL);
        __builtin_nontemporal_store(v_sc,  out + o + 3 * PL);

        v = new_v; a = new_a; lsd = new_lsd; z = zs;

        {
            unsigned long long wm = __ballot(zs != 0.f);
            if (lane == 0) msk[rb ^ 1][wid] = wm;
        }
        __syncthreads();
    }
}

// ---------------------------------------------------------------------------
// Fallback scan (R1 version) — used only if ws_size is too small.
// ---------------------------------------------------------------------------
__global__ __launch_bounds__(256) void lsnn_scan_fb_kernel(
    const float* __restrict__ xin,   // x [B,T,NI]
    const float* __restrict__ w_in,
    const float* __restrict__ w_rec,
    const float* __restrict__ z0, const float* __restrict__ v0,
    const float* __restrict__ a0, const float* __restrict__ lsd0,
    float* __restrict__ out)
{
    const int b    = blockIdx.x;
    const int n    = threadIdx.x;
    const int lane = n & 63;
    const int wid  = n >> 6;

    __shared__ int   cnt4[4];
    __shared__ int   act[256];
    __shared__ float xsh[256];

    const float dv   = (float)0.9512294245007140018;
    const float omdv = 1.0f - dv;

    const int base_bn = b * N_NEUR + n;
    float z   = z0[base_bn];
    float v   = v0[base_bn];
    float a   = a0[base_bn];
    float lsd = lsd0[base_bn];

    act[n] = 0;
    {
        unsigned long long wm = __ballot(z != 0.f);
        if (lane == 0) cnt4[wid] = __popcll(wm);
        if (z != 0.f) {
            int pos = __popcll(wm & ((1ull << lane) - 1ull));
            act[wid * 64 + pos] = n;
        }
        xsh[n] = xin[((size_t)b * T_STEPS) * N_IN + n];
    }
    __syncthreads();

    for (int t = 0; t < T_STEPS; ++t) {
        const int cs0 = cnt4[0], cs1 = cnt4[1], cs2 = cnt4[2], cs3 = cnt4[3];
        int mx = max(max(cs0, cs1), max(cs2, cs3));
        float r0 = 0.f, r1 = 0.f, r2 = 0.f, r3 = 0.f;
        for (int i0 = 0; i0 < mx; i0 += 8) {
            float wv[4][8];
            bool  ok[4][8];
#pragma unroll
            for (int s = 0; s < 4; ++s) {
                const int cs = (s == 0) ? cs0 : (s == 1) ? cs1 : (s == 2) ? cs2 : cs3;
#pragma unroll
                for (int j = 0; j < 8; ++j) {
                    int ii = i0 + j;
                    int m  = act[s * 64 + (ii < cs ? ii : 0)] & 255;
                    wv[s][j] = w_rec[m * N_NEUR + n];
                    ok[s][j] = (ii < cs) && (m != n);
                }
            }
#pragma unroll
            for (int j = 0; j < 8; ++j) r0 += ok[0][j] ? wv[0][j] : 0.f;
#pragma unroll
            for (int j = 0; j < 8; ++j) r1 += ok[1][j] ? wv[1][j] : 0.f;
#pragma unroll
            for (int j = 0; j < 8; ++j) r2 += ok[2][j] ? wv[2][j] : 0.f;
#pragma unroll
            for (int j = 0; j < 8; ++j) r3 += ok[3][j] ? wv[3][j] : 0.f;
        }
        float i_rec = ((r0 + r1) + r2) + r3;

        float s = 0.f;
#pragma unroll 8
        for (int m = 0; m < N_IN; ++m) s += xsh[m] * w_in[m * N_NEUR + n];
        float i_in = s + i_rec;

        float new_a = dv * a + omdv * z;
        float thr   = 0.03f + new_a * 1.8f;
        float new_v = dv * v + omdv * i_in - thr * z;
        float v_sc  = (new_v - thr) / thr;
        float zs    = (v_sc > 0.f) ? 1.f : 0.f;
        zs          = (lsd >= 2.0f) ? zs : 0.f;
        float new_lsd = (lsd + 1.f) * (1.f - zs);

        const size_t PL = (size_t)T_STEPS * N_BATCH * N_NEUR;
        size_t o = (size_t)t * (N_BATCH * N_NEUR) + (size_t)b * N_NEUR + n;
        out[o]          = zs;
        out[o + PL]     = new_v;
        out[o + 2 * PL] = thr;
        out[o + 3 * PL] = v_sc;

        v = new_v; a = new_a; lsd = new_lsd; z = zs;

        __syncthreads();
        unsigned long long wm = __ballot(zs != 0.f);
        if (lane == 0) cnt4[wid] = __popcll(wm);
        if (zs != 0.f) {
            int pos = __popcll(wm & ((1ull << lane) - 1ull));
            act[wid * 64 + pos] = n;
        }
        if (t + 1 < T_STEPS)
            xsh[n] = xin[((size_t)b * T_STEPS + t + 1) * N_IN + n];
        __syncthreads();
    }
}

// ---------------------------------------------------------------------------
extern "C" void kernel_launch(void* const* d_in, const int* in_sizes, int n_in,
                              void* d_out, int out_size, void* d_ws, size_t ws_size,
                              hipStream_t stream) {
    const float* x     = (const float*)d_in[0];
    const float* w_in  = (const float*)d_in[1];
    const float* w_rec = (const float*)d_in[2];
    const float* z0    = (const float*)d_in[3];
    const float* v0    = (const float*)d_in[4];
    const float* a0    = (const float*)d_in[5];
    const float* lsd0  = (const float*)d_in[6];
    float* out = (float*)d_out;

    const size_t xw_bytes = (size_t)N_BATCH * T_STEPS * N_NEUR * sizeof(float);
    const size_t wz_bytes = (size_t)257 * 256 * sizeof(float);

    if (ws_size >= xw_bytes + wz_bytes) {
        float* xw = (float*)d_ws;
        float* wz = (float*)((char*)d_ws + xw_bytes);
        prep_wrec_kernel<<<257, 256, 0, stream>>>(w_rec, wz);
        dim3 grid(500, 2, 1);
        xw_gemm2_kernel<<<grid, 256, 0, stream>>>(x, w_in, xw);
        lsnn_scan4_kernel<<<N_BATCH, 256, 0, stream>>>(
            xw, wz, z0, v0, a0, lsd0, out);
    } else {
        lsnn_scan_fb_kernel<<<N_BATCH, 256, 0, stream>>>(
            x, w_in, w_rec, z0, v0, a0, lsd0, out);
    }
}